// Round 21
// baseline (66.918 us; speedup 1.0000x reference)
//
#include <hip/hip_runtime.h>

typedef __attribute__((ext_vector_type(8))) short short8;
typedef __attribute__((ext_vector_type(4))) float f32x4;
typedef __attribute__((ext_vector_type(16))) float f32x16;

#define MFMA_B16(a, b, c) __builtin_amdgcn_mfma_f32_16x16x32_bf16((a), (b), (c), 0, 0, 0)
#define MFMA32(a, b, c) __builtin_amdgcn_mfma_f32_32x32x16_bf16((a), (b), (c), 0, 0, 0)

#define NTOK 2048
#define DM 256
#define NB4 4
#define HD 64

__device__ __forceinline__ short f2bf(float f) {
  union { float f; unsigned u; } x;
  x.f = f;
  unsigned r = x.u + 0x7fffu + ((x.u >> 16) & 1u);
  return (short)(r >> 16);
}
__device__ __forceinline__ float bf2f(short s) {
  union { unsigned u; float f; } x;
  x.u = ((unsigned)(unsigned short)s) << 16;
  return x.f;
}
// fp32[8] -> bf16x8 (two float4 loads + pack)
__device__ __forceinline__ short8 ldw8(const float* p) {
  float4 a = *(const float4*)p, b = *(const float4*)(p + 4);
  short8 r;
  r[0] = f2bf(a.x); r[1] = f2bf(a.y); r[2] = f2bf(a.z); r[3] = f2bf(a.w);
  r[4] = f2bf(b.x); r[5] = f2bf(b.y); r[6] = f2bf(b.z); r[7] = f2bf(b.w);
  return r;
}

// async global->LDS, 16B per lane. LDS dest = uniform base + lane*16 (HW).
__device__ __forceinline__ void gload16(const short* g, short* l) {
  __builtin_amdgcn_global_load_lds(
      (const __attribute__((address_space(1))) void*)g,
      (__attribute__((address_space(3))) void*)l, 16, 0, 0);
}

// Fused transpose + projection. Block = 64 n-rows x all 256 c, one (tau,b).
// Weights converted fp32->bf16 on the fly (ldw8); tau==2,b==0 blocks emit the
// head-major bf16 wm for k_out (consumed next launch, no ordering hazard).
// Epilogue: results staged into the free As LDS buffer at block-local
// fragment-linear offsets, then copied out with fully coalesced short8 stores.
// Fragment layouts (lane32 = idx&31):
//  Q/K: addr(n,d) = (((bh*64 + n>>5)*4 + d>>4)*64 + (n&31) + 32*((d>>3)&1))*8 + (d&7)
//  V:   addr(d,m) = (((bh*128 + m>>4)*2 + d>>5)*64 + (d&31) + 32*((m>>3)&1))*8 + (m&7)
__global__ __launch_bounds__(256, 4) void k_proj(const float* __restrict__ q,
    const float* __restrict__ k, const float* __restrict__ v,
    const float* __restrict__ wq, const float* __restrict__ wk,
    const float* __restrict__ wv, const float* __restrict__ wm,
    const float* __restrict__ bq, const float* __restrict__ bk,
    const float* __restrict__ bv, short* __restrict__ qt,
    short* __restrict__ kt, short* __restrict__ vt, short* __restrict__ wmbf) {
  __shared__ __align__(16) short As[16384];  // 32KB: GEMM operand, then epilogue stage
  int z = blockIdx.y, b = z & 3, tau = z >> 2;
  const float* src = ((tau == 0) ? q : (tau == 1) ? k : v) + (size_t)b * DM * NTOK;
  const float* W = (tau == 0) ? wq : (tau == 1) ? wk : wv;
  const float* bias = (tau == 0) ? bq : (tau == 1) ? bk : bv;
  int n0 = blockIdx.x * 64;
  int t = threadIdx.x;
  // ---- wm head-major conversion (32 blocks x 2048 elems, once) ----
  if (tau == 2 && b == 0) {
    int off = blockIdx.x * 2048 + t * 8;
    int c = off >> 8, ip = off & 255;
    const float* srow = wm + (size_t)c * 256;
    short8 r;
#pragma unroll
    for (int j = 0; j < 8; j++) {
      int i2 = ip + j;
      r[j] = f2bf(srow[4 * (i2 & 63) + (i2 >> 6)]);
    }
    *(short8*)(wmbf + off) = r;
  }
  // ---- stage: read fp32 (full lines), convert, swizzled LDS write ----
  {
    int nseg = t & 15, rg = t >> 4;
#pragma unroll
    for (int outer = 0; outer < 2; outer++) {
      int iG = rg + 16 * outer;       // i-granule 0..31
      const float* s0 = src + (size_t)(iG * 8) * NTOK + n0 + nseg * 4;
      float4 rows[8];
#pragma unroll
      for (int j = 0; j < 8; j++) rows[j] = *(const float4*)(s0 + (size_t)j * NTOK);
      int i32 = iG >> 2, fhi = iG & 3, s = iG & 7;
#pragma unroll
      for (int e = 0; e < 4; e++) {
        int n = nseg * 4 + e;
        int nb = n >> 4, flo = n & 15;
        short8 r;
#pragma unroll
        for (int j = 0; j < 8; j++)
          r[j] = f2bf(e == 0 ? rows[j].x : e == 1 ? rows[j].y
                                         : e == 2 ? rows[j].z : rows[j].w);
        int frag = ((nb * 8 + i32) * 64 + fhi * 16 + flo) ^ s;
        *(short8*)(As + frag * 8) = r;
      }
    }
  }
  __syncthreads();
  // ---- GEMM: wave = 64 c x 64 n, acc[cb][nb]; W loaded fp32 + packed ----
  int lane = t & 63, w = t >> 6;
  int lo = lane & 15, hi = lane >> 4;
  f32x4 acc[4][4] = {};
  const float* wrow = W + (size_t)(64 * w + lo) * DM + hi * 8;
#pragma unroll
  for (int ks = 0; ks < 8; ks++) {
    int sr = hi | ((ks & 1) << 2);
    short8 xf[4];
#pragma unroll
    for (int nb = 0; nb < 4; nb++) {
      int frag = ((nb * 8 + ks) * 64 + lane) ^ sr;
      xf[nb] = *(const short8*)(As + frag * 8);
    }
#pragma unroll
    for (int cb = 0; cb < 4; cb++) {
      short8 wf = ldw8(wrow + (size_t)cb * 16 * DM + ks * 32);
      if (tau < 2) {
#pragma unroll
        for (int nb = 0; nb < 4; nb++)
          acc[cb][nb] = MFMA_B16(xf[nb], wf, acc[cb][nb]);   // col=c, row=n
      } else {
#pragma unroll
        for (int nb = 0; nb < 4; nb++)
          acc[cb][nb] = MFMA_B16(wf, xf[nb], acc[cb][nb]);   // col=n, row=c
      }
    }
  }
  __syncthreads();   // all GEMM reads of As done; reuse As for epilogue staging
  if (tau < 2) {
    short* out = tau ? kt : qt;
    float scale = tau ? 1.0f : (0.125f * 1.44269504f);  // fold 1/sqrt(64), log2e into Q
#pragma unroll
    for (int cb = 0; cb < 4; cb++) {
      int c = 64 * w + 16 * cb + lo;
      float bvv = bias[c];
      int h = c & 3, d = c >> 2;
      int dterm = (d >> 4) * 512 + ((d >> 3) & 1) * 256 + (d & 7);
#pragma unroll
      for (int nb = 0; nb < 4; nb++) {
#pragma unroll
        for (int r = 0; r < 4; r++) {
          int np = 16 * nb + 4 * hi + r;   // local n 0..63
          int loc = (h * 2 + (np >> 5)) * 2048 + dterm + (np & 31) * 8;
          As[loc] = f2bf((acc[cb][nb][r] + bvv) * scale);
        }
      }
    }
    __syncthreads();
    // coalesced copy-out: 8 runs of 2048 shorts; wave w does runs 2w, 2w+1
#pragma unroll
    for (int rr = 0; rr < 2; rr++) {
      int qr = w * 2 + rr;               // run = h*2 + n32p
      int h = qr >> 1, n32p = qr & 1;
      size_t gbase = ((size_t)(b * 4 + h) * 64 + (n0 >> 5) + n32p) * 2048;
      int lbase = qr * 2048;
#pragma unroll
      for (int it = 0; it < 4; it++)
        *(short8*)(out + gbase + it * 512 + lane * 8) =
            *(const short8*)(As + lbase + it * 512 + lane * 8);
    }
  } else {
#pragma unroll
    for (int cb = 0; cb < 4; cb++) {
#pragma unroll
      for (int r = 0; r < 4; r++) {
        int c = 64 * w + 16 * cb + 4 * hi + r;
        float bvv = bias[c];
        int h = c & 3, d = c >> 2;
        int dterm = (d >> 5) * 512 + (d & 31) * 8;
#pragma unroll
        for (int nb = 0; nb < 4; nb++) {
          int mp = 16 * nb + lo;          // local m 0..63
          int loc = (h * 4 + (mp >> 4)) * 1024 + dterm + ((mp >> 3) & 1) * 256 + (mp & 7);
          As[loc] = f2bf(acc[cb][nb][r] + bvv);
        }
      }
    }
    __syncthreads();
    // coalesced copy-out: 4 runs of 4096 shorts (one per h); wave w does h=w
    {
      size_t gbase = ((size_t)(b * 4 + w) * 128 + (n0 >> 4)) * 1024;
      int lbase = w * 4096;
#pragma unroll
      for (int it = 0; it < 8; it++)
        *(short8*)(vt + gbase + it * 512 + lane * 8) =
            *(const short8*)(As + lbase + it * 512 + lane * 8);
    }
  }
}

// Flash attention, 32x32x16 MFMA, fully in-register P. 8 waves x 32 n = 256-row
// Q tiles. Swapped QK^T; P redistributed via v_cvt_pk_bf16_f32 + permlane32_swap.
// No-max softmax; per-lane row-sum + one shfl_xor(32).
// T4 pipeline: 3-deep LDS buffers, counted s_waitcnt vmcnt(2) + RAW s_barrier.
// Epilogue: Opart staged through the freed K/V LDS (wave-private 4KB region,
// opart-linear) then copied out with fully coalesced short8 stores.
// SPLIT==4: XCD-aware 1-D decode (T1, bijective).
template <int SPLIT>
__global__ __launch_bounds__(512, 4) void k_attn(const short* __restrict__ qt,
    const short* __restrict__ kt, const short* __restrict__ vt,
    short* __restrict__ opart, float* __restrict__ ml) {
  __shared__ __align__(16) short SMEM[24576];   // 48KB: 3xKs(8KB) + 3xVs(8KB); epilogue
  short (*Ks)[4096] = (short(*)[4096])SMEM;          // [m32(2)][dk(4)][lane][8]
  short (*Vs)[4096] = (short(*)[4096])(SMEM + 12288); // [m16(4)][dcol(2)][lane][8]
  int b, h, chunk, n0;
  if (SPLIT == 4) {
    int bid = blockIdx.x;
    int xcd = bid & 7, slot = bid >> 3;
    int g = xcd + 8 * (slot >> 3);    // group 0..63, g%8 == xcd
    n0 = (slot & 7) * 256;            // q-tile within group
    h = g & 3;
    int zz = g >> 2;                  // 0..15
    b = zz & 3;
    chunk = zz >> 2;
  } else {
    b = blockIdx.z & 3; chunk = 0; h = blockIdx.y; n0 = blockIdx.x * 256;
  }
  int tid = threadIdx.x;
  int lane = tid & 63, w = tid >> 6;
  int l31 = lane & 31, hi2 = lane >> 5;
  const int CH = NTOK / SPLIT;
  const int kv0 = chunk * CH;
  int bh = b * 4 + h;
  const short* Qf = qt + (size_t)bh * 131072;
  const short* Kf = kt + (size_t)bh * 131072;
  const short* Vf = vt + (size_t)bh * 131072;
  short8 qf[4];
#pragma unroll
  for (int dk = 0; dk < 4; dk++)
    qf[dk] = *(const short8*)(Qf + (((size_t)((n0 >> 5) + w) * 4 + dk) * 64 + lane) * 8);
  f32x16 acc[2] = {};
  float lacc = 0.0f;

  const int nt = CH >> 6;   // 8 (SPLIT=4) or 32 (SPLIT=1)
  // prologue: stage tiles 0 and 1, one-time full drain
  {
    int m0 = kv0;
    gload16(Kf + (size_t)(m0 >> 5) * 2048 + tid * 8, &Ks[0][tid * 8]);
    gload16(Vf + (size_t)(m0 >> 4) * 1024 + tid * 8, &Vs[0][tid * 8]);
    int m1 = kv0 + 64;
    gload16(Kf + (size_t)(m1 >> 5) * 2048 + tid * 8, &Ks[1][tid * 8]);
    gload16(Vf + (size_t)(m1 >> 4) * 1024 + tid * 8, &Vs[1][tid * 8]);
  }
  asm volatile("s_waitcnt vmcnt(0)" ::: "memory");
  __builtin_amdgcn_s_barrier();
  __builtin_amdgcn_sched_barrier(0);

#pragma unroll
  for (int t = 0; t < nt; t++) {
    int cur = t % 3;
    if (t + 2 < nt) {
      int m2 = kv0 + ((t + 2) << 6);
      int nxt = (t + 2) % 3;
      gload16(Kf + (size_t)(m2 >> 5) * 2048 + tid * 8, &Ks[nxt][tid * 8]);
      gload16(Vf + (size_t)(m2 >> 4) * 1024 + tid * 8, &Vs[nxt][tid * 8]);
    }
#pragma unroll
    for (int mb2 = 0; mb2 < 2; mb2++) {
      // ---- QK^T: S[m 32][n 32], chained over 4 k-slices of d ----
      f32x16 s = {};
      __builtin_amdgcn_s_setprio(1);
#pragma unroll
      for (int dk = 0; dk < 4; dk++) {
        short8 kf = *(const short8*)&Ks[cur][(mb2 * 4 + dk) * 512 + lane * 8];
        s = MFMA32(kf, qf[dk], s);
      }
      __builtin_amdgcn_s_setprio(0);
      // ---- softmax + in-register P->A redistribution + PV ----
#pragma unroll
      for (int ks = 0; ks < 2; ks++) {
        float e0 = exp2f(s[ks * 8 + 0]), e1 = exp2f(s[ks * 8 + 1]);
        float e2 = exp2f(s[ks * 8 + 2]), e3 = exp2f(s[ks * 8 + 3]);
        float e4 = exp2f(s[ks * 8 + 4]), e5 = exp2f(s[ks * 8 + 5]);
        float e6 = exp2f(s[ks * 8 + 6]), e7 = exp2f(s[ks * 8 + 7]);
        lacc += ((e0 + e1) + (e2 + e3)) + ((e4 + e5) + (e6 + e7));
        unsigned A, B, C2, D2;
        asm("v_cvt_pk_bf16_f32 %0, %1, %2" : "=v"(A) : "v"(e0), "v"(e1));
        asm("v_cvt_pk_bf16_f32 %0, %1, %2" : "=v"(C2) : "v"(e2), "v"(e3));
        asm("v_cvt_pk_bf16_f32 %0, %1, %2" : "=v"(B) : "v"(e4), "v"(e5));
        asm("v_cvt_pk_bf16_f32 %0, %1, %2" : "=v"(D2) : "v"(e6), "v"(e7));
        // swap: A' = (A_lo, B_lo) = pa w0;  B' = (A_hi, B_hi) = pa w2
        asm("v_permlane32_swap_b32 %0, %1" : "+v"(A), "+v"(B));
        asm("v_permlane32_swap_b32 %0, %1" : "+v"(C2), "+v"(D2));
        union { unsigned u[4]; short8 v8; } pu;
        pu.u[0] = A; pu.u[1] = C2; pu.u[2] = B; pu.u[3] = D2;
        __builtin_amdgcn_s_setprio(1);
#pragma unroll
        for (int dcol = 0; dcol < 2; dcol++) {
          short8 vf = *(const short8*)&Vs[cur][((mb2 * 2 + ks) * 2 + dcol) * 512 + lane * 8];
          acc[dcol] = MFMA32(pu.v8, vf, acc[dcol]);
        }
        __builtin_amdgcn_s_setprio(0);
      }
    }
    // counted wait: ensure tile t+1 resident; keep t+2's loads in flight.
    if (t + 1 < nt) {
      if (t + 2 < nt)
        asm volatile("s_waitcnt vmcnt(2) lgkmcnt(0)" ::: "memory");
      else
        asm volatile("s_waitcnt vmcnt(0) lgkmcnt(0)" ::: "memory");
      __builtin_amdgcn_s_barrier();
      __builtin_amdgcn_sched_barrier(0);
    }
  }

  // row-sum: combine the two lane-halves (same n at lane and lane^32)
  float l = lacc + __shfl_xor(lacc, 32);
  size_t rbase = (((size_t)chunk * NB4 + b) * 4 + h) * NTOK;
  if (lane < 32) ml[rbase + n0 + 32 * w + lane] = l;

  // ---- epilogue: stage O into freed SMEM (wave-private), coalesced copy-out ----
  __syncthreads();   // other waves may still be reading their final K/V tile
  short* Eo = SMEM + w * 2048;   // 32 rows x 64 d, opart-linear
#pragma unroll
  for (int r = 0; r < 16; r++) {
    int nl = (r & 3) + 8 * (r >> 2) + 4 * hi2;   // local row 0..31
#pragma unroll
    for (int dcol = 0; dcol < 2; dcol++)
      Eo[nl * 64 + dcol * 32 + l31] = f2bf(acc[dcol][r]);
  }
  // wave-private region: ds_write -> ds_read ordered by lgkmcnt, no barrier
  size_t gbase = (rbase + n0 + 32 * w) * HD;
#pragma unroll
  for (int it = 0; it < 4; it++)
    *(short8*)(opart + gbase + it * 512 + lane * 8) =
        *(const short8*)(Eo + it * 512 + lane * 8);
}

// Fused combine + output GEMM, c-split for occupancy: block = 32 n x 128 c,
// grid (64, 8) = 512 blocks = 2/CU (was 256 = 1/CU). Combine->As staging is
// c-independent (needs all 256 i') so c-split duplicates only the L2-warm
// Opart read (+16MB), NOT the W cost (r19 trap avoided: W per unique output
// unchanged). Wave w -> c-slab 64*(w&1), n-half 16*(w>>1); acc[4].
template <int NCH>
__global__ __launch_bounds__(256, 4) void k_out(const short* __restrict__ W,
    const short* __restrict__ opart, const float* __restrict__ ml,
    const float* __restrict__ bias, float* __restrict__ outp) {
  __shared__ __align__(16) short As[8192];  // [nb(2)][i32(8)][64][8], swizzled
  int yz = blockIdx.y, b = yz & 3, c0 = (yz >> 2) * 128;
  int n0 = blockIdx.x * 32;
  int t = threadIdx.x;
  int lane = t & 63, w = t >> 6;
  int lo16 = lane & 15, hi = lane >> 4;
  {
    int d8 = t & 7, h = (t >> 3) & 3, nb8 = t >> 5;   // nb8 0..7
    int i32 = 2 * h + (d8 >> 2), fhi = d8 & 3;        // fragment coords of i'
#pragma unroll
    for (int it = 0; it < 4; it++) {
      int noff = nb8 * 4 + it;                        // 0..31
      int n = n0 + noff;
      int nb = noff >> 4, flo = noff & 15;
      size_t row0 = ((size_t)b * 4 + h) * NTOK + n;   // chunk 0
      float l = ml[row0];
      float o[8];
      short8 o0 = *(const short8*)(opart + row0 * HD + d8 * 8);
#pragma unroll
      for (int j = 0; j < 8; j++) o[j] = bf2f(o0[j]);
#pragma unroll
      for (int ch = 1; ch < NCH; ch++) {
        size_t rowc = row0 + (size_t)ch * 16 * NTOK;
        l += ml[rowc];
        short8 oc = *(const short8*)(opart + rowc * HD + d8 * 8);
#pragma unroll
        for (int j = 0; j < 8; j++) o[j] += bf2f(oc[j]);
      }
      float inv = 1.0f / l;
      short8 res;
#pragma unroll
      for (int j = 0; j < 8; j++) res[j] = f2bf(o[j] * inv);
      int frag = ((nb * 8 + i32) * 64 + fhi * 16 + flo) ^ d8;  // d8==fhi|((i32&1)<<2)
      *(short8*)(As + frag * 8) = res;
    }
  }
  __syncthreads();
  f32x4 acc[4] = {};   // [cb]
  int cw = c0 + 64 * (w & 1);   // wave's 64-c slab
  int nb = w >> 1;              // wave's 16-row n-half
  const short* arow = W + (size_t)(cw + lo16) * DM + hi * 8;
#pragma unroll
  for (int ks = 0; ks < 8; ks++) {
    int sr = hi | ((ks & 1) << 2);
    int frag = ((nb * 8 + ks) * 64 + lane) ^ sr;
    short8 bbr = *(const short8*)(As + frag * 8);
#pragma unroll
    for (int cb = 0; cb < 4; cb++) {
      short8 a = *(const short8*)(arow + (size_t)cb * 16 * DM + ks * 32);
      acc[cb] = MFMA_B16(a, bbr, acc[cb]);
    }
  }
#pragma unroll
  for (int cb = 0; cb < 4; cb++) {
#pragma unroll
    for (int r = 0; r < 4; r++) {
      int c = cw + 16 * cb + 4 * hi + r;
      float bvv = bias[c];
      int n = n0 + 16 * nb + lo16;
      outp[((size_t)b * DM + c) * NTOK + n] = acc[cb][r] + bvv;
    }
  }
}

extern "C" void kernel_launch(void* const* d_in, const int* in_sizes, int n_in,
                              void* d_out, int out_size, void* d_ws, size_t ws_size,
                              hipStream_t stream) {
  const float* q  = (const float*)d_in[0];
  const float* k  = (const float*)d_in[1];
  const float* v  = (const float*)d_in[2];
  const float* wq = (const float*)d_in[3];
  const float* bq = (const float*)d_in[4];
  const float* wk = (const float*)d_in[5];
  const float* bk = (const float*)d_in[6];
  const float* wv = (const float*)d_in[7];
  const float* bv = (const float*)d_in[8];
  const float* wm = (const float*)d_in[9];
  const float* bm = (const float*)d_in[10];

  char* ws = (char*)d_ws;
  const size_t MB = 1024 * 1024;
  short* Qt   = (short*)(ws);             // 4MB  Q fragments (32-wide)
  short* Kt   = (short*)(ws + 4 * MB);    // 4MB  K fragments
  short* Vt   = (short*)(ws + 8 * MB);    // 4MB  V fragments
  short* Wmbf = (short*)(ws + 12 * MB);   // 128KB head-major bf16 wm
  float* ML    = (float*)(ws + 13 * MB);  // 4 chunks x 128KB row sums l
  short* Opart = (short*)(ws + 14 * MB);  // 4 chunks x 4MB bf16 partial O

  k_proj<<<dim3(32, 12), 256, 0, stream>>>(q, k, v, wq, wk, wv, wm,
                                           bq, bk, bv, Qt, Kt, Vt, Wmbf);

  if (ws_size >= 32 * MB) {
    k_attn<4><<<dim3(512), 512, 0, stream>>>(Qt, Kt, Vt, Opart, ML);
    k_out<4><<<dim3(64, 8), 256, 0, stream>>>(Wmbf, Opart, ML, bm, (float*)d_out);
  } else {
    k_attn<1><<<dim3(8, 4, 4), 512, 0, stream>>>(Qt, Kt, Vt, Opart, ML);
    k_out<1><<<dim3(64, 8), 256, 0, stream>>>(Wmbf, Opart, ML, bm, (float*)d_out);
  }

  (void)in_sizes; (void)n_in; (void)out_size; (void)ws_size;
}

// Round 22
// 63.931 us; speedup vs baseline: 1.0467x; 1.0467x over previous
//
#include <hip/hip_runtime.h>

typedef __attribute__((ext_vector_type(8))) short short8;
typedef __attribute__((ext_vector_type(4))) float f32x4;
typedef __attribute__((ext_vector_type(16))) float f32x16;

#define MFMA_B16(a, b, c) __builtin_amdgcn_mfma_f32_16x16x32_bf16((a), (b), (c), 0, 0, 0)
#define MFMA32(a, b, c) __builtin_amdgcn_mfma_f32_32x32x16_bf16((a), (b), (c), 0, 0, 0)

#define NTOK 2048
#define DM 256
#define NB4 4
#define HD 64

__device__ __forceinline__ short f2bf(float f) {
  union { float f; unsigned u; } x;
  x.f = f;
  unsigned r = x.u + 0x7fffu + ((x.u >> 16) & 1u);
  return (short)(r >> 16);
}
__device__ __forceinline__ float bf2f(short s) {
  union { unsigned u; float f; } x;
  x.u = ((unsigned)(unsigned short)s) << 16;
  return x.f;
}
// fp32[8] -> bf16x8 (two float4 loads + pack)
__device__ __forceinline__ short8 ldw8(const float* p) {
  float4 a = *(const float4*)p, b = *(const float4*)(p + 4);
  short8 r;
  r[0] = f2bf(a.x); r[1] = f2bf(a.y); r[2] = f2bf(a.z); r[3] = f2bf(a.w);
  r[4] = f2bf(b.x); r[5] = f2bf(b.y); r[6] = f2bf(b.z); r[7] = f2bf(b.w);
  return r;
}

// async global->LDS, 16B per lane. LDS dest = uniform base + lane*16 (HW).
__device__ __forceinline__ void gload16(const short* g, short* l) {
  __builtin_amdgcn_global_load_lds(
      (const __attribute__((address_space(1))) void*)g,
      (__attribute__((address_space(3))) void*)l, 16, 0, 0);
}

// Fused transpose + projection. Block = 64 n-rows x all 256 c, one (tau,b).
// Weights converted fp32->bf16 on the fly (ldw8); tau==2,b==0 blocks emit the
// head-major bf16 wm for k_out (consumed next launch, no ordering hazard).
// Epilogue: results staged into the free As LDS buffer at block-local
// fragment-linear offsets, then copied out with fully coalesced short8 stores.
// Fragment layouts (lane32 = idx&31):
//  Q/K: addr(n,d) = (((bh*64 + n>>5)*4 + d>>4)*64 + (n&31) + 32*((d>>3)&1))*8 + (d&7)
//  V:   addr(d,m) = (((bh*128 + m>>4)*2 + d>>5)*64 + (d&31) + 32*((m>>3)&1))*8 + (m&7)
__global__ __launch_bounds__(256, 4) void k_proj(const float* __restrict__ q,
    const float* __restrict__ k, const float* __restrict__ v,
    const float* __restrict__ wq, const float* __restrict__ wk,
    const float* __restrict__ wv, const float* __restrict__ wm,
    const float* __restrict__ bq, const float* __restrict__ bk,
    const float* __restrict__ bv, short* __restrict__ qt,
    short* __restrict__ kt, short* __restrict__ vt, short* __restrict__ wmbf) {
  __shared__ __align__(16) short As[16384];  // 32KB: GEMM operand, then epilogue stage
  int z = blockIdx.y, b = z & 3, tau = z >> 2;
  const float* src = ((tau == 0) ? q : (tau == 1) ? k : v) + (size_t)b * DM * NTOK;
  const float* W = (tau == 0) ? wq : (tau == 1) ? wk : wv;
  const float* bias = (tau == 0) ? bq : (tau == 1) ? bk : bv;
  int n0 = blockIdx.x * 64;
  int t = threadIdx.x;
  // ---- wm head-major conversion (32 blocks x 2048 elems, once) ----
  if (tau == 2 && b == 0) {
    int off = blockIdx.x * 2048 + t * 8;
    int c = off >> 8, ip = off & 255;
    const float* srow = wm + (size_t)c * 256;
    short8 r;
#pragma unroll
    for (int j = 0; j < 8; j++) {
      int i2 = ip + j;
      r[j] = f2bf(srow[4 * (i2 & 63) + (i2 >> 6)]);
    }
    *(short8*)(wmbf + off) = r;
  }
  // ---- stage: read fp32 (full lines), convert, swizzled LDS write ----
  {
    int nseg = t & 15, rg = t >> 4;
#pragma unroll
    for (int outer = 0; outer < 2; outer++) {
      int iG = rg + 16 * outer;       // i-granule 0..31
      const float* s0 = src + (size_t)(iG * 8) * NTOK + n0 + nseg * 4;
      float4 rows[8];
#pragma unroll
      for (int j = 0; j < 8; j++) rows[j] = *(const float4*)(s0 + (size_t)j * NTOK);
      int i32 = iG >> 2, fhi = iG & 3, s = iG & 7;
#pragma unroll
      for (int e = 0; e < 4; e++) {
        int n = nseg * 4 + e;
        int nb = n >> 4, flo = n & 15;
        short8 r;
#pragma unroll
        for (int j = 0; j < 8; j++)
          r[j] = f2bf(e == 0 ? rows[j].x : e == 1 ? rows[j].y
                                         : e == 2 ? rows[j].z : rows[j].w);
        int frag = ((nb * 8 + i32) * 64 + fhi * 16 + flo) ^ s;
        *(short8*)(As + frag * 8) = r;
      }
    }
  }
  __syncthreads();
  // ---- GEMM: wave = 64 c x 64 n, acc[cb][nb]; W loaded fp32 + packed ----
  int lane = t & 63, w = t >> 6;
  int lo = lane & 15, hi = lane >> 4;
  f32x4 acc[4][4] = {};
  const float* wrow = W + (size_t)(64 * w + lo) * DM + hi * 8;
#pragma unroll
  for (int ks = 0; ks < 8; ks++) {
    int sr = hi | ((ks & 1) << 2);
    short8 xf[4];
#pragma unroll
    for (int nb = 0; nb < 4; nb++) {
      int frag = ((nb * 8 + ks) * 64 + lane) ^ sr;
      xf[nb] = *(const short8*)(As + frag * 8);
    }
#pragma unroll
    for (int cb = 0; cb < 4; cb++) {
      short8 wf = ldw8(wrow + (size_t)cb * 16 * DM + ks * 32);
      if (tau < 2) {
#pragma unroll
        for (int nb = 0; nb < 4; nb++)
          acc[cb][nb] = MFMA_B16(xf[nb], wf, acc[cb][nb]);   // col=c, row=n
      } else {
#pragma unroll
        for (int nb = 0; nb < 4; nb++)
          acc[cb][nb] = MFMA_B16(wf, xf[nb], acc[cb][nb]);   // col=n, row=c
      }
    }
  }
  __syncthreads();   // all GEMM reads of As done; reuse As for epilogue staging
  if (tau < 2) {
    short* out = tau ? kt : qt;
    float scale = tau ? 1.0f : (0.125f * 1.44269504f);  // fold 1/sqrt(64), log2e into Q
#pragma unroll
    for (int cb = 0; cb < 4; cb++) {
      int c = 64 * w + 16 * cb + lo;
      float bvv = bias[c];
      int h = c & 3, d = c >> 2;
      int dterm = (d >> 4) * 512 + ((d >> 3) & 1) * 256 + (d & 7);
#pragma unroll
      for (int nb = 0; nb < 4; nb++) {
#pragma unroll
        for (int r = 0; r < 4; r++) {
          int np = 16 * nb + 4 * hi + r;   // local n 0..63
          int loc = (h * 2 + (np >> 5)) * 2048 + dterm + (np & 31) * 8;
          As[loc] = f2bf((acc[cb][nb][r] + bvv) * scale);
        }
      }
    }
    __syncthreads();
    // coalesced copy-out: 8 runs of 2048 shorts; wave w does runs 2w, 2w+1
#pragma unroll
    for (int rr = 0; rr < 2; rr++) {
      int qr = w * 2 + rr;               // run = h*2 + n32p
      int h = qr >> 1, n32p = qr & 1;
      size_t gbase = ((size_t)(b * 4 + h) * 64 + (n0 >> 5) + n32p) * 2048;
      int lbase = qr * 2048;
#pragma unroll
      for (int it = 0; it < 4; it++)
        *(short8*)(out + gbase + it * 512 + lane * 8) =
            *(const short8*)(As + lbase + it * 512 + lane * 8);
    }
  } else {
#pragma unroll
    for (int cb = 0; cb < 4; cb++) {
#pragma unroll
      for (int r = 0; r < 4; r++) {
        int c = 64 * w + 16 * cb + 4 * hi + r;
        float bvv = bias[c];
        int h = c & 3, d = c >> 2;
        int dterm = (d >> 5) * 512 + (d & 31) * 8;
#pragma unroll
        for (int nb = 0; nb < 4; nb++) {
          int mp = 16 * nb + lo;          // local m 0..63
          int loc = (h * 4 + (mp >> 4)) * 1024 + dterm + ((mp >> 3) & 1) * 256 + (mp & 7);
          As[loc] = f2bf(acc[cb][nb][r] + bvv);
        }
      }
    }
    __syncthreads();
    // coalesced copy-out: 4 runs of 4096 shorts (one per h); wave w does h=w
    {
      size_t gbase = ((size_t)(b * 4 + w) * 128 + (n0 >> 4)) * 1024;
      int lbase = w * 4096;
#pragma unroll
      for (int it = 0; it < 8; it++)
        *(short8*)(vt + gbase + it * 512 + lane * 8) =
            *(const short8*)(As + lbase + it * 512 + lane * 8);
    }
  }
}

// Flash attention, 32x32x16 MFMA, fully in-register P. 8 waves x 32 n = 256-row
// Q tiles. Swapped QK^T; P redistributed via v_cvt_pk_bf16_f32 + permlane32_swap.
// No-max softmax; per-lane row-sum + one shfl_xor(32).
// T4 pipeline: 3-deep LDS buffers, counted s_waitcnt vmcnt(2) + RAW s_barrier.
// Epilogue: Opart staged through the freed K/V LDS (wave-private 4KB region,
// opart-linear) then copied out with fully coalesced short8 stores.
// SPLIT==4: XCD-aware 1-D decode (T1, bijective).
template <int SPLIT>
__global__ __launch_bounds__(512, 4) void k_attn(const short* __restrict__ qt,
    const short* __restrict__ kt, const short* __restrict__ vt,
    short* __restrict__ opart, float* __restrict__ ml) {
  __shared__ __align__(16) short SMEM[24576];   // 48KB: 3xKs(8KB) + 3xVs(8KB); epilogue
  short (*Ks)[4096] = (short(*)[4096])SMEM;          // [m32(2)][dk(4)][lane][8]
  short (*Vs)[4096] = (short(*)[4096])(SMEM + 12288); // [m16(4)][dcol(2)][lane][8]
  int b, h, chunk, n0;
  if (SPLIT == 4) {
    int bid = blockIdx.x;
    int xcd = bid & 7, slot = bid >> 3;
    int g = xcd + 8 * (slot >> 3);    // group 0..63, g%8 == xcd
    n0 = (slot & 7) * 256;            // q-tile within group
    h = g & 3;
    int zz = g >> 2;                  // 0..15
    b = zz & 3;
    chunk = zz >> 2;
  } else {
    b = blockIdx.z & 3; chunk = 0; h = blockIdx.y; n0 = blockIdx.x * 256;
  }
  int tid = threadIdx.x;
  int lane = tid & 63, w = tid >> 6;
  int l31 = lane & 31, hi2 = lane >> 5;
  const int CH = NTOK / SPLIT;
  const int kv0 = chunk * CH;
  int bh = b * 4 + h;
  const short* Qf = qt + (size_t)bh * 131072;
  const short* Kf = kt + (size_t)bh * 131072;
  const short* Vf = vt + (size_t)bh * 131072;
  short8 qf[4];
#pragma unroll
  for (int dk = 0; dk < 4; dk++)
    qf[dk] = *(const short8*)(Qf + (((size_t)((n0 >> 5) + w) * 4 + dk) * 64 + lane) * 8);
  f32x16 acc[2] = {};
  float lacc = 0.0f;

  const int nt = CH >> 6;   // 8 (SPLIT=4) or 32 (SPLIT=1)
  // prologue: stage tiles 0 and 1, one-time full drain
  {
    int m0 = kv0;
    gload16(Kf + (size_t)(m0 >> 5) * 2048 + tid * 8, &Ks[0][tid * 8]);
    gload16(Vf + (size_t)(m0 >> 4) * 1024 + tid * 8, &Vs[0][tid * 8]);
    int m1 = kv0 + 64;
    gload16(Kf + (size_t)(m1 >> 5) * 2048 + tid * 8, &Ks[1][tid * 8]);
    gload16(Vf + (size_t)(m1 >> 4) * 1024 + tid * 8, &Vs[1][tid * 8]);
  }
  asm volatile("s_waitcnt vmcnt(0)" ::: "memory");
  __builtin_amdgcn_s_barrier();
  __builtin_amdgcn_sched_barrier(0);

#pragma unroll
  for (int t = 0; t < nt; t++) {
    int cur = t % 3;
    if (t + 2 < nt) {
      int m2 = kv0 + ((t + 2) << 6);
      int nxt = (t + 2) % 3;
      gload16(Kf + (size_t)(m2 >> 5) * 2048 + tid * 8, &Ks[nxt][tid * 8]);
      gload16(Vf + (size_t)(m2 >> 4) * 1024 + tid * 8, &Vs[nxt][tid * 8]);
    }
#pragma unroll
    for (int mb2 = 0; mb2 < 2; mb2++) {
      // ---- QK^T: S[m 32][n 32], chained over 4 k-slices of d ----
      f32x16 s = {};
      __builtin_amdgcn_s_setprio(1);
#pragma unroll
      for (int dk = 0; dk < 4; dk++) {
        short8 kf = *(const short8*)&Ks[cur][(mb2 * 4 + dk) * 512 + lane * 8];
        s = MFMA32(kf, qf[dk], s);
      }
      __builtin_amdgcn_s_setprio(0);
      // ---- softmax + in-register P->A redistribution + PV ----
#pragma unroll
      for (int ks = 0; ks < 2; ks++) {
        float e0 = exp2f(s[ks * 8 + 0]), e1 = exp2f(s[ks * 8 + 1]);
        float e2 = exp2f(s[ks * 8 + 2]), e3 = exp2f(s[ks * 8 + 3]);
        float e4 = exp2f(s[ks * 8 + 4]), e5 = exp2f(s[ks * 8 + 5]);
        float e6 = exp2f(s[ks * 8 + 6]), e7 = exp2f(s[ks * 8 + 7]);
        lacc += ((e0 + e1) + (e2 + e3)) + ((e4 + e5) + (e6 + e7));
        unsigned A, B, C2, D2;
        asm("v_cvt_pk_bf16_f32 %0, %1, %2" : "=v"(A) : "v"(e0), "v"(e1));
        asm("v_cvt_pk_bf16_f32 %0, %1, %2" : "=v"(C2) : "v"(e2), "v"(e3));
        asm("v_cvt_pk_bf16_f32 %0, %1, %2" : "=v"(B) : "v"(e4), "v"(e5));
        asm("v_cvt_pk_bf16_f32 %0, %1, %2" : "=v"(D2) : "v"(e6), "v"(e7));
        // swap: A' = (A_lo, B_lo) = pa w0;  B' = (A_hi, B_hi) = pa w2
        asm("v_permlane32_swap_b32 %0, %1" : "+v"(A), "+v"(B));
        asm("v_permlane32_swap_b32 %0, %1" : "+v"(C2), "+v"(D2));
        union { unsigned u[4]; short8 v8; } pu;
        pu.u[0] = A; pu.u[1] = C2; pu.u[2] = B; pu.u[3] = D2;
        __builtin_amdgcn_s_setprio(1);
#pragma unroll
        for (int dcol = 0; dcol < 2; dcol++) {
          short8 vf = *(const short8*)&Vs[cur][((mb2 * 2 + ks) * 2 + dcol) * 512 + lane * 8];
          acc[dcol] = MFMA32(pu.v8, vf, acc[dcol]);
        }
        __builtin_amdgcn_s_setprio(0);
      }
    }
    // counted wait: ensure tile t+1 resident; keep t+2's loads in flight.
    if (t + 1 < nt) {
      if (t + 2 < nt)
        asm volatile("s_waitcnt vmcnt(2) lgkmcnt(0)" ::: "memory");
      else
        asm volatile("s_waitcnt vmcnt(0) lgkmcnt(0)" ::: "memory");
      __builtin_amdgcn_s_barrier();
      __builtin_amdgcn_sched_barrier(0);
    }
  }

  // row-sum: combine the two lane-halves (same n at lane and lane^32)
  float l = lacc + __shfl_xor(lacc, 32);
  size_t rbase = (((size_t)chunk * NB4 + b) * 4 + h) * NTOK;
  if (lane < 32) ml[rbase + n0 + 32 * w + lane] = l;

  // ---- epilogue: stage O into freed SMEM (wave-private), coalesced copy-out ----
  __syncthreads();   // other waves may still be reading their final K/V tile
  short* Eo = SMEM + w * 2048;   // 32 rows x 64 d, opart-linear
#pragma unroll
  for (int r = 0; r < 16; r++) {
    int nl = (r & 3) + 8 * (r >> 2) + 4 * hi2;   // local row 0..31
#pragma unroll
    for (int dcol = 0; dcol < 2; dcol++)
      Eo[nl * 64 + dcol * 32 + l31] = f2bf(acc[dcol][r]);
  }
  // wave-private region: ds_write -> ds_read ordered by lgkmcnt, no barrier
  size_t gbase = (rbase + n0 + 32 * w) * HD;
#pragma unroll
  for (int it = 0; it < 4; it++)
    *(short8*)(opart + gbase + it * 512 + lane * 8) =
        *(const short8*)(Eo + it * 512 + lane * 8);
}

// Fused combine + output GEMM, c0-merged: block = 32 n-rows x ALL 256 c.
// Additive combine -> As (fragment-linear, XOR-swizzled); wave = 64c x 32n.
template <int NCH>
__global__ __launch_bounds__(256, 4) void k_out(const short* __restrict__ W,
    const short* __restrict__ opart, const float* __restrict__ ml,
    const float* __restrict__ bias, float* __restrict__ outp) {
  __shared__ __align__(16) short As[8192];  // [nb(2)][i32(8)][64][8], swizzled
  int b = blockIdx.y;
  int n0 = blockIdx.x * 32;
  int t = threadIdx.x;
  int lane = t & 63, w = t >> 6;
  int lo16 = lane & 15, hi = lane >> 4;
  {
    int d8 = t & 7, h = (t >> 3) & 3, nb8 = t >> 5;   // nb8 0..7
    int i32 = 2 * h + (d8 >> 2), fhi = d8 & 3;        // fragment coords of i'
#pragma unroll
    for (int it = 0; it < 4; it++) {
      int noff = nb8 * 4 + it;                        // 0..31
      int n = n0 + noff;
      int nb = noff >> 4, flo = noff & 15;
      size_t row0 = ((size_t)b * 4 + h) * NTOK + n;   // chunk 0
      float l = ml[row0];
      float o[8];
      short8 o0 = *(const short8*)(opart + row0 * HD + d8 * 8);
#pragma unroll
      for (int j = 0; j < 8; j++) o[j] = bf2f(o0[j]);
#pragma unroll
      for (int ch = 1; ch < NCH; ch++) {
        size_t rowc = row0 + (size_t)ch * 16 * NTOK;
        l += ml[rowc];
        short8 oc = *(const short8*)(opart + rowc * HD + d8 * 8);
#pragma unroll
        for (int j = 0; j < 8; j++) o[j] += bf2f(oc[j]);
      }
      float inv = 1.0f / l;
      short8 res;
#pragma unroll
      for (int j = 0; j < 8; j++) res[j] = f2bf(o[j] * inv);
      int frag = ((nb * 8 + i32) * 64 + fhi * 16 + flo) ^ d8;  // d8==fhi|((i32&1)<<2)
      *(short8*)(As + frag * 8) = res;
    }
  }
  __syncthreads();
  f32x4 acc[4][2] = {};   // [cb][nb]
  const short* arow = W + (size_t)(64 * w + lo16) * DM + hi * 8;
#pragma unroll
  for (int ks = 0; ks < 8; ks++) {
    int sr = hi | ((ks & 1) << 2);
    short8 bbr[2];
#pragma unroll
    for (int nb = 0; nb < 2; nb++) {
      int frag = ((nb * 8 + ks) * 64 + lane) ^ sr;
      bbr[nb] = *(const short8*)(As + frag * 8);
    }
#pragma unroll
    for (int cb = 0; cb < 4; cb++) {
      short8 a = *(const short8*)(arow + (size_t)cb * 16 * DM + ks * 32);
#pragma unroll
      for (int nb = 0; nb < 2; nb++)
        acc[cb][nb] = MFMA_B16(a, bbr[nb], acc[cb][nb]);
    }
  }
#pragma unroll
  for (int cb = 0; cb < 4; cb++) {
#pragma unroll
    for (int r = 0; r < 4; r++) {
      int c = 64 * w + 16 * cb + 4 * hi + r;
      float bvv = bias[c];
#pragma unroll
      for (int nb = 0; nb < 2; nb++) {
        int n = n0 + 16 * nb + lo16;
        outp[((size_t)b * DM + c) * NTOK + n] = acc[cb][nb][r] + bvv;
      }
    }
  }
}

extern "C" void kernel_launch(void* const* d_in, const int* in_sizes, int n_in,
                              void* d_out, int out_size, void* d_ws, size_t ws_size,
                              hipStream_t stream) {
  const float* q  = (const float*)d_in[0];
  const float* k  = (const float*)d_in[1];
  const float* v  = (const float*)d_in[2];
  const float* wq = (const float*)d_in[3];
  const float* bq = (const float*)d_in[4];
  const float* wk = (const float*)d_in[5];
  const float* bk = (const float*)d_in[6];
  const float* wv = (const float*)d_in[7];
  const float* bv = (const float*)d_in[8];
  const float* wm = (const float*)d_in[9];
  const float* bm = (const float*)d_in[10];

  char* ws = (char*)d_ws;
  const size_t MB = 1024 * 1024;
  short* Qt   = (short*)(ws);             // 4MB  Q fragments (32-wide)
  short* Kt   = (short*)(ws + 4 * MB);    // 4MB  K fragments
  short* Vt   = (short*)(ws + 8 * MB);    // 4MB  V fragments
  short* Wmbf = (short*)(ws + 12 * MB);   // 128KB head-major bf16 wm
  float* ML    = (float*)(ws + 13 * MB);  // 4 chunks x 128KB row sums l
  short* Opart = (short*)(ws + 14 * MB);  // 4 chunks x 4MB bf16 partial O

  k_proj<<<dim3(32, 12), 256, 0, stream>>>(q, k, v, wq, wk, wv, wm,
                                           bq, bk, bv, Qt, Kt, Vt, Wmbf);

  if (ws_size >= 32 * MB) {
    k_attn<4><<<dim3(512), 512, 0, stream>>>(Qt, Kt, Vt, Opart, ML);
    k_out<4><<<dim3(64, 4), 256, 0, stream>>>(Wmbf, Opart, ML, bm, (float*)d_out);
  } else {
    k_attn<1><<<dim3(8, 4, 4), 512, 0, stream>>>(Qt, Kt, Vt, Opart, ML);
    k_out<1><<<dim3(64, 4), 256, 0, stream>>>(Wmbf, Opart, ML, bm, (float*)d_out);
  }

  (void)in_sizes; (void)n_in; (void)out_size; (void)ws_size;
}